// Round 4
// baseline (2833.965 us; speedup 1.0000x reference)
//
#include <hip/hip_runtime.h>
#include <math.h>

#define BATCH 4096
#define LDIM 1024
#define HDIM 2048
#define ODIM 512
#define GDIM 3072   // 3*LDIM
#define JDIM 1536   // IDIM+ODIM == LDIM+ODIM
#define INNER 4
#define OUTER 8

using f16 = _Float16;
using f16x4 = __attribute__((ext_vector_type(4))) _Float16;
using f16x8 = __attribute__((ext_vector_type(8))) _Float16;
using f32x4 = __attribute__((ext_vector_type(4))) float;

typedef __attribute__((address_space(3))) void lds_void;
typedef __attribute__((address_space(1))) void glob_void;

__device__ __forceinline__ void gload16(const void* g, void* l) {
  __builtin_amdgcn_global_load_lds((const glob_void*)g, (lds_void*)l, 16, 0, 0);
}

#define MFMA16(a, b, c) __builtin_amdgcn_mfma_f32_16x16x32_f16(a, b, c, 0, 0, 0)
// counted vmcnt wait: keeps prefetch loads in flight across raw s_barrier
#define WAIT_VM(N) asm volatile("s_waitcnt vmcnt(" #N ")" ::: "memory")
#define SBAR asm volatile("s_barrier" ::: "memory")

__device__ __forceinline__ float fast_sigmoid(float x) {
  return __builtin_amdgcn_rcpf(1.0f + __expf(-x));
}
__device__ __forceinline__ float fast_tanh(float x) {
  return 1.0f - 2.0f * __builtin_amdgcn_rcpf(1.0f + __expf(2.0f * x));
}

// fp32 -> fp16 (RTN), n4 = elems/4
__global__ __launch_bounds__(256) void convert_w(const float* __restrict__ src,
                                                 f16* __restrict__ dst, int n4) {
  int i = blockIdx.x * 256 + threadIdx.x;
  if (i >= n4) return;
  float4 v = ((const float4*)src)[i];
  f16x4 d = {(f16)v.x, (f16)v.y, (f16)v.z, (f16)v.w};
  *(f16x4*)&dst[(size_t)i * 4] = d;
}

// inputs [B,1024] fp32 -> cols [0,1024) of catX [B,1536] fp16
__global__ __launch_bounds__(256) void input_to_cat(
    const float* __restrict__ inp, f16* __restrict__ cH) {
  int idx = blockIdx.x * 256 + threadIdx.x;  // over B*256 float4s
  if (idx >= BATCH * 256) return;
  int row = idx >> 8, c4 = idx & 255;
  float4 v = ((const float4*)inp)[idx];
  f16x4 h4 = {(f16)v.x, (f16)v.y, (f16)v.z, (f16)v.w};
  *(f16x4*)&cH[(size_t)row * JDIM + c4 * 4] = h4;
}

// ============================================================================
// 8-phase 256x256 fp16 GEMM (HK-style schedule in plain HIP).
// C[4096, N] = epi(A @ W^T + bias). A fp16 [M][K], W fp16 [N][K].
// 512 threads = 8 waves (2M x 4N); wave output 128x64 = acc[8][4] frags.
// BK=64 split into 2 K-halves of 32; LDS = 2 dbuf x 2 khalf x 256x32 x {A,W}
// = 128 KB. Per K-tile: 4 phases = (kk, m-half) quadrants of 16 MFMA; each
// phase stages ONE half-tile of tile t+1 into buf[p^1] (2 gload16/thread).
// vmcnt(4)+barrier at phases 0/2 drains exactly the 2 half-tiles those
// phases read, leaving 2 half-tiles in flight (never vmcnt(0) mid-loop).
// Read-side XOR swizzle (quad ^ ((fr>>1)&3)) matched by pre-swizzled global
// source column (both-sides rule); LDS dest stays linear for global_load_lds.
// EPI: 0 = PACKED fp16 C ([m/4][N][4]);  1 = joint head relu (h1 f16/h2 f32)
// ============================================================================
template <int EPI>
__global__ __launch_bounds__(512, 1) void gemm_f16(
    const f16* __restrict__ A, const f16* __restrict__ W,
    const float* __restrict__ bias, const float* __restrict__ bias2,
    f16* __restrict__ Ch, float* __restrict__ Cf, int N, int K) {
  __shared__ f16 sA[2 * 2 * 256 * 32];  // 64 KB
  __shared__ f16 sW[2 * 2 * 256 * 32];  // 64 KB
  const int tid = threadIdx.x;
  const int w = tid >> 6, lane = tid & 63;
  const int wm = w >> 2, wn = w & 3;
  const int fr = lane & 15, quad = lane >> 4;
  const int nb = N >> 8;
  const int m0 = (blockIdx.x / nb) * 256, n0 = (blockIdx.x % nb) * 256;

  // staging: thread t covers row tid>>2 (and +128), 16B chunk tid&3,
  // source column pre-swizzled to match the read-side XOR.
  const int swz_src = (((tid & 3) ^ ((tid >> 3) & 3)) * 8);
  const f16* pAst = A + (size_t)(m0 + (tid >> 2)) * K + swz_src;
  const f16* pWst = W + (size_t)(n0 + (tid >> 2)) * K + swz_src;
  const size_t h128 = (size_t)128 * K;
  const int ldst = tid * 8;  // f16 elems; = lane*16B within wave ✓
  // read-side swizzle (row>>1)&3 == (fr>>1)&3 for 16-aligned frag rows
  const int swr = ((quad ^ ((fr >> 1) & 3)) * 8);

  f32x4 acc[8][4] = {};
  const int NT = K >> 6;  // K-tiles of 64

#define STA(p, kh, kt)                                              \
  {                                                                 \
    int o = ((p) * 2 + (kh)) * 8192 + ldst;                         \
    gload16(pAst + (kt) * 64 + (kh) * 32, &sA[o]);                  \
    gload16(pAst + h128 + (kt) * 64 + (kh) * 32, &sA[o + 4096]);    \
  }
#define STW(p, kh, kt)                                              \
  {                                                                 \
    int o = ((p) * 2 + (kh)) * 8192 + ldst;                         \
    gload16(pWst + (kt) * 64 + (kh) * 32, &sW[o]);                  \
    gload16(pWst + h128 + (kt) * 64 + (kh) * 32, &sW[o + 4096]);    \
  }
#define LDB(p, kk)                                                  \
  _Pragma("unroll") for (int j = 0; j < 4; ++j) {                   \
    int rn = wn * 64 + j * 16 + fr;                                 \
    bf[j] = *(const f16x8*)&sW[((p) * 2 + (kk)) * 8192 + rn * 32 + swr]; \
  }
#define LDA(p, kk, mh)                                              \
  _Pragma("unroll") for (int i2 = 0; i2 < 4; ++i2) {                \
    int rm = wm * 128 + (mh) * 64 + i2 * 16 + fr;                   \
    af[i2] = *(const f16x8*)&sA[((p) * 2 + (kk)) * 8192 + rm * 32 + swr]; \
  }
#define DOMFMA(mh)                                                  \
  __builtin_amdgcn_s_setprio(1);                                    \
  _Pragma("unroll") for (int i2 = 0; i2 < 4; ++i2)                  \
  _Pragma("unroll") for (int j = 0; j < 4; ++j)                     \
      acc[(mh) * 4 + i2][j] = MFMA16(af[i2], bf[j], acc[(mh) * 4 + i2][j]); \
  __builtin_amdgcn_s_setprio(0);

  // prologue: stage all 4 half-tiles of tile 0 into buf 0 (8 loads)
  STA(0, 0, 0); STW(0, 0, 0); STA(0, 1, 0); STW(0, 1, 0);

  for (int t = 0; t < NT; ++t) {
    const int p = t & 1, pn = p ^ 1;
    const bool pf = (t + 1 < NT);
    f16x8 af[4], bf[4];
    // ---- phase 0: kk=0, mh=0; stage A-h0(t+1)
    if (t == NT - 1) { WAIT_VM(0); } else { WAIT_VM(4); }
    SBAR;
    if (pf) STA(pn, 0, t + 1);
    LDB(p, 0); LDA(p, 0, 0);
    DOMFMA(0);
    // ---- phase 1: kk=0, mh=1; stage W-h0(t+1); bf reused
    SBAR;
    if (pf) STW(pn, 0, t + 1);
    LDA(p, 0, 1);
    DOMFMA(1);
    // ---- phase 2: kk=1, mh=0; stage A-h1(t+1)
    if (t == NT - 1) { WAIT_VM(0); } else { WAIT_VM(4); }
    SBAR;
    if (pf) STA(pn, 1, t + 1);
    LDB(p, 1); LDA(p, 1, 0);
    DOMFMA(0);
    // ---- phase 3: kk=1, mh=1; stage W-h1(t+1); bf reused
    SBAR;
    if (pf) STW(pn, 1, t + 1);
    LDA(p, 1, 1);
    DOMFMA(1);
  }
#undef STA
#undef STW
#undef LDB
#undef LDA
#undef DOMFMA

  // C/D map: col = lane&15, row = quad*4 + reg
  bool is_h1 = true;
  const float* bp = bias;
  int nb0 = n0;
  if (EPI == 1) {
    is_h1 = (n0 < 2048);
    bp = is_h1 ? bias : bias2;
    nb0 = is_h1 ? n0 : n0 - 2048;
  }
#pragma unroll
  for (int j = 0; j < 4; ++j) {
    int n = nb0 + wn * 64 + j * 16 + fr;
    float bv = bp[n];
#pragma unroll
    for (int i = 0; i < 8; ++i) {
      int mb = m0 + wm * 128 + i * 16 + quad * 4;
      if (EPI == 0) {
        f16x4 o = {(f16)(acc[i][j][0] + bv), (f16)(acc[i][j][1] + bv),
                   (f16)(acc[i][j][2] + bv), (f16)(acc[i][j][3] + bv)};
        *(f16x4*)&Ch[((size_t)(mb >> 2) * N + n) * 4] = o;
      } else {
#pragma unroll
        for (int r = 0; r < 4; ++r) {
          int m = mb + r;
          float v = fmaxf(acc[i][j][r] + bv, 0.0f);
          if (is_h1)
            Ch[(size_t)m * HDIM + n] = (f16)v;
          else
            Cf[(size_t)m * LDIM + n] = v;
        }
      }
    }
  }
}

// ============================================================================
// Logits GEMM (N=512, K=2048): 128x128 tile, triple-buffer counted vmcnt.
// fp32 out + tanh -> fp16 into catX/catJ ans cols.
// ============================================================================
__global__ __launch_bounds__(256, 2) void gemm_logits(
    const f16* __restrict__ A, const f16* __restrict__ W,
    const float* __restrict__ bias, float* __restrict__ Cout,
    f16* __restrict__ aXH, f16* __restrict__ aJH, int N, int K) {
  __shared__ f16 sA[3][128 * 32];
  __shared__ f16 sW[3][128 * 32];
  const int tid = threadIdx.x;
  const int w = tid >> 6, lane = tid & 63;
  const int wm = w >> 1, wn = w & 1;
  const int fr = lane & 15, quad = lane >> 4;
  const int m0 = blockIdx.y * 128, n0 = blockIdx.x * 128;
  const int srow = w * 32 + (lane >> 2);
  const int scol = (((lane & 3) ^ ((lane >> 3) & 3)) * 8);
  const f16* pA = A + (size_t)(m0 + srow) * K + scol;
  const f16* pW = W + (size_t)(n0 + srow) * K + scol;
  const size_t rstep = (size_t)16 * K;
  const int lo = w * 1024;

  f32x4 acc[4][4] = {};
  const int NT = K >> 5;

  auto stage = [&](int b, int k) {
    gload16(pA + k, &sA[b][lo]);
    gload16(pA + rstep + k, &sA[b][lo + 512]);
    gload16(pW + k, &sW[b][lo]);
    gload16(pW + rstep + k, &sW[b][lo + 512]);
  };
  stage(0, 0);
  stage(1, 32);
  int bb = 0;
  for (int t = 0; t < NT; ++t) {
    if (t == NT - 1) { WAIT_VM(0); } else { WAIT_VM(4); }
    __builtin_amdgcn_s_barrier();
    if (t + 2 < NT) {
      int bn = bb + 2; if (bn >= 3) bn -= 3;
      stage(bn, (t + 2) * 32);
    }
    f16x8 af[4], bf[4];
#pragma unroll
    for (int i = 0; i < 4; ++i) {
      int rr = wm * 64 + i * 16 + fr;
      af[i] = *(const f16x8*)&sA[bb][rr * 32 + ((quad ^ ((rr >> 1) & 3)) << 3)];
    }
#pragma unroll
    for (int j = 0; j < 4; ++j) {
      int rr = wn * 64 + j * 16 + fr;
      bf[j] = *(const f16x8*)&sW[bb][rr * 32 + ((quad ^ ((rr >> 1) & 3)) << 3)];
    }
    __builtin_amdgcn_s_setprio(1);
#pragma unroll
    for (int i = 0; i < 4; ++i)
#pragma unroll
      for (int j = 0; j < 4; ++j) acc[i][j] = MFMA16(af[i], bf[j], acc[i][j]);
    __builtin_amdgcn_s_setprio(0);
    if (++bb == 3) bb = 0;
  }

#pragma unroll
  for (int j = 0; j < 4; ++j) {
    int n = n0 + wn * 64 + j * 16 + fr;
    float bv = bias[n];
#pragma unroll
    for (int i = 0; i < 4; ++i) {
      int mb = m0 + wm * 64 + i * 16 + quad * 4;
#pragma unroll
      for (int r = 0; r < 4; ++r) {
        int m = mb + r;
        float v = acc[i][j][r] + bv;
        Cout[(size_t)m * N + n] = v;
        f16 t = (f16)fast_tanh(v);
        size_t c = (size_t)m * JDIM + 1024 + n;
        aXH[c] = t;
        aJH[c] = t;
      }
    }
  }
}

// ============================================================================
// Fused GRU cycle: h_gates = state @ W_hh^T + b_hh (r,z,n) + gate update.
// Block: 128(M) x 64(N per gate) x 3 gates. 4 waves, wave = 32(M)x64(N).
// Triple-buffer + counted vmcnt(5) + LDS swizzle. 1D grid with XCD decode:
// each XCD owns 2 n-blocks -> its W_hh slice (768KB) is L2-resident across
// all 32 GRU dispatches.
// ============================================================================
__global__ __launch_bounds__(256, 2) void gru_fused(
    const f16* __restrict__ inH, const f16* __restrict__ Whh,
    const float* __restrict__ bhh, const f16* __restrict__ xgP,
    f16* __restrict__ outH, f16* __restrict__ catJH) {
  __shared__ f16 sA[3][128 * 32];
  __shared__ f16 sW0[3][64 * 32];
  __shared__ f16 sW1[3][64 * 32];
  __shared__ f16 sW2[3][64 * 32];
  const int tid = threadIdx.x;
  const int w = tid >> 6, lane = tid & 63;
  const int fr = lane & 15, quad = lane >> 4;
  // XCD decode: 8 XCDs x (2 n-blocks x 32 m-blocks)
  const int flat = blockIdx.x;
  const int xcd = flat & 7, local = flat >> 3;
  const int n0 = (xcd * 2 + (local & 1)) * 64;
  const int m0 = (local >> 1) * 128;
  const int srow = w * 32 + (lane >> 2);
  const int scol = (((lane & 3) ^ ((lane >> 3) & 3)) * 8);  // swizzled source
  const f16* pA = inH + (size_t)(m0 + srow) * LDIM + scol;
  const size_t rstepA = (size_t)16 * LDIM;
  const int wrow = w * 16 + (lane >> 2);
  const f16* pW0 = Whh + (size_t)(n0 + wrow) * LDIM + scol;
  const f16* pW1 = pW0 + (size_t)LDIM * LDIM;
  const f16* pW2 = pW1 + (size_t)LDIM * LDIM;
  const int loA = w * 1024, loW = w * 512;

  f32x4 ar[2][4] = {}, az[2][4] = {}, an_[2][4] = {};
  const int NT = LDIM >> 5;  // 32

  auto stage = [&](int b, int k) {
    gload16(pA + k, &sA[b][loA]);
    gload16(pA + rstepA + k, &sA[b][loA + 512]);
    gload16(pW0 + k, &sW0[b][loW]);
    gload16(pW1 + k, &sW1[b][loW]);
    gload16(pW2 + k, &sW2[b][loW]);
  };
  stage(0, 0);
  stage(1, 32);
  int bb = 0;
  for (int t = 0; t < NT; ++t) {
    if (t == NT - 1) { WAIT_VM(0); } else { WAIT_VM(5); }
    __builtin_amdgcn_s_barrier();
    if (t + 2 < NT) {
      int bn = bb + 2; if (bn >= 3) bn -= 3;
      stage(bn, (t + 2) * 32);
    }
    f16x8 a_[2], w0[4], w1[4], w2[4];
#pragma unroll
    for (int i = 0; i < 2; ++i) {
      int rr = w * 32 + i * 16 + fr;
      a_[i] = *(const f16x8*)&sA[bb][rr * 32 + ((quad ^ ((rr >> 1) & 3)) << 3)];
    }
#pragma unroll
    for (int j = 0; j < 4; ++j) {
      int rw = j * 16 + fr;
      int wo = rw * 32 + ((quad ^ ((rw >> 1) & 3)) << 3);
      w0[j] = *(const f16x8*)&sW0[bb][wo];
      w1[j] = *(const f16x8*)&sW1[bb][wo];
      w2[j] = *(const f16x8*)&sW2[bb][wo];
    }
    __builtin_amdgcn_s_setprio(1);
#pragma unroll
    for (int i = 0; i < 2; ++i)
#pragma unroll
      for (int j = 0; j < 4; ++j) {
        ar[i][j] = MFMA16(a_[i], w0[j], ar[i][j]);
        az[i][j] = MFMA16(a_[i], w1[j], az[i][j]);
        an_[i][j] = MFMA16(a_[i], w2[j], an_[i][j]);
      }
    __builtin_amdgcn_s_setprio(0);
    if (++bb == 3) bb = 0;
  }

  // epilogue: full GRU gate update; xg loads are f16x4 (packed layout)
#pragma unroll
  for (int j = 0; j < 4; ++j) {
    int col = n0 + j * 16 + fr;
    float br = bhh[col], bz = bhh[col + LDIM], bn = bhh[col + 2 * LDIM];
#pragma unroll
    for (int i = 0; i < 2; ++i) {
      int mb = m0 + w * 32 + i * 16 + quad * 4;
      size_t xb = ((size_t)(mb >> 2) * GDIM + col) * 4;
      f16x4 x4r = *(const f16x4*)&xgP[xb];
      f16x4 x4z = *(const f16x4*)&xgP[xb + (size_t)LDIM * 4];
      f16x4 x4n = *(const f16x4*)&xgP[xb + (size_t)2 * LDIM * 4];
#pragma unroll
      for (int r = 0; r < 4; ++r) {
        int m = mb + r;
        size_t si = (size_t)m * LDIM + col;
        float sold = (float)inH[si];
        float rg = fast_sigmoid((float)x4r[r] + ar[i][j][r] + br);
        float zg = fast_sigmoid((float)x4z[r] + az[i][j][r] + bz);
        float ng = fast_tanh((float)x4n[r] + rg * (an_[i][j][r] + bn));
        float o = (1.0f - zg) * ng + zg * sold;
        f16 oh = (f16)o;
        outH[si] = oh;
        if (catJH) catJH[(size_t)m * JDIM + col] = oh;
      }
    }
  }
}

// halt = h2[B,1024] @ hw2[2,1024]^T + hb2; one wave per row.
__global__ __launch_bounds__(256) void halt_kernel(
    const float* __restrict__ h2, const float* __restrict__ hw2,
    const float* __restrict__ hb2, float* __restrict__ out) {
  int wave = (blockIdx.x * 256 + threadIdx.x) >> 6;
  int lane = threadIdx.x & 63;
  if (wave >= BATCH) return;
  const float* row = h2 + (size_t)wave * LDIM;
  float s0 = 0.0f, s1 = 0.0f;
#pragma unroll
  for (int k = lane; k < LDIM; k += 64) {
    float v = row[k];
    s0 = fmaf(v, hw2[k], s0);
    s1 = fmaf(v, hw2[LDIM + k], s1);
  }
#pragma unroll
  for (int off = 32; off > 0; off >>= 1) {
    s0 += __shfl_xor(s0, off);
    s1 += __shfl_xor(s1, off);
  }
  if (lane == 0) {
    out[(size_t)wave * 2 + 0] = s0 + hb2[0];
    out[(size_t)wave * 2 + 1] = s1 + hb2[1];
  }
}

extern "C" void kernel_launch(void* const* d_in, const int* in_sizes, int n_in,
                              void* d_out, int out_size, void* d_ws, size_t ws_size,
                              hipStream_t stream) {
  const float* inputs = (const float*)d_in[0];
  const float* W_ih = (const float*)d_in[1];
  const float* W_hh = (const float*)d_in[2];
  const float* b_ih = (const float*)d_in[3];
  const float* b_hh = (const float*)d_in[4];
  const float* aw1 = (const float*)d_in[5];
  const float* ab1 = (const float*)d_in[6];
  const float* aw2 = (const float*)d_in[7];
  const float* ab2 = (const float*)d_in[8];
  const float* hw1 = (const float*)d_in[9];
  const float* hb1 = (const float*)d_in[10];
  const float* hw2 = (const float*)d_in[11];
  const float* hb2 = (const float*)d_in[12];

  float* out = (float*)d_out;
  float* logits_out = out;                               // [8, B, 512]
  float* halt_out = out + (size_t)OUTER * BATCH * ODIM;  // [8, B, 2]

  char* p = (char*)d_ws;
  auto take = [&](size_t bytes) { char* q = p; p += (bytes + 255) & ~255ull; return q; };
  f16* stA = (f16*)take((size_t)BATCH * LDIM * 2);
  f16* stB = (f16*)take((size_t)BATCH * LDIM * 2);
  f16* catX = (f16*)take((size_t)BATCH * JDIM * 2);
  f16* catJ = (f16*)take((size_t)BATCH * JDIM * 2);
  f16* xg = (f16*)take((size_t)BATCH * GDIM * 2);       // 25 MB, PACKED layout
  float* h2F = (float*)take((size_t)BATCH * LDIM * 4);
  f16* WihF = (f16*)take((size_t)GDIM * JDIM * 2);
  f16* WhhF = (f16*)take((size_t)GDIM * LDIM * 2);
  f16* WjF = (f16*)take((size_t)(HDIM + LDIM) * JDIM * 2);  // [aw1; hw1]
  f16* aw2F = (f16*)take((size_t)ODIM * HDIM * 2);
  // overlay: h1 fp16 [B,2048] lives in xg region (xg dead after GRU cycles,
  // h1 dead before next step's xg GEMM)
  f16* h1 = xg;

  (void)hipMemsetAsync(stA, 0, (size_t)BATCH * LDIM * 2, stream);
  (void)hipMemsetAsync(catX, 0, (size_t)BATCH * JDIM * 2, stream);
  (void)hipMemsetAsync(catJ, 0, (size_t)BATCH * JDIM * 2, stream);

  auto conv = [&](const float* s, f16* d, size_t n) {
    int n4 = (int)(n / 4);
    convert_w<<<(n4 + 255) / 256, 256, 0, stream>>>(s, d, n4);
  };
  conv(W_ih, WihF, (size_t)GDIM * JDIM);
  conv(W_hh, WhhF, (size_t)GDIM * LDIM);
  conv(aw1, WjF, (size_t)HDIM * JDIM);
  conv(hw1, WjF + (size_t)HDIM * JDIM, (size_t)LDIM * JDIM);
  conv(aw2, aw2F, (size_t)ODIM * HDIM);
  input_to_cat<<<BATCH, 256, 0, stream>>>(inputs, catX);

  for (int s = 0; s < OUTER; ++s) {
    // x_gates = [inputs|ans] @ W_ih^T + b_ih -> PACKED fp16 xg
    gemm_f16<0><<<(BATCH / 256) * (GDIM / 256), 512, 0, stream>>>(
        catX, WihF, b_ih, nullptr, xg, nullptr, GDIM, JDIM);
    // 4 fused GRU cycles, ping-pong; last writes catJ state cols
    f16 *cur = stA, *nxt = stB;
    for (int c = 0; c < INNER; ++c) {
      bool last = (c == INNER - 1);
      gru_fused<<<512, 256, 0, stream>>>(
          cur, WhhF, b_hh, xg, nxt, last ? catJ : nullptr);
      f16* t = cur; cur = nxt; nxt = t;
    }
    // h1 = relu(joint @ aw1^T + ab1) fp16 (overlay xg);
    // h2 = relu(joint @ hw1^T + hb1) fp32 — one combined N=3072 GEMM
    gemm_f16<1><<<(BATCH / 256) * ((HDIM + LDIM) / 256), 512, 0, stream>>>(
        catJ, WjF, ab1, hb1, h1, h2F, HDIM + LDIM, JDIM);
    // logits = h1 @ aw2^T + ab2 -> out; ans = tanh -> catX/catJ ans cols
    gemm_logits<<<dim3(ODIM / 128, BATCH / 128), 256, 0, stream>>>(
        h1, aw2F, ab2, logits_out + (size_t)s * BATCH * ODIM, catX, catJ,
        ODIM, HDIM);
    // halt = h2 @ hw2^T + hb2 -> out
    halt_kernel<<<BATCH / 4, 256, 0, stream>>>(
        h2F, hw2, hb2, halt_out + (size_t)s * BATCH * 2);
  }
}

// Round 6
// 2531.594 us; speedup vs baseline: 1.1194x; 1.1194x over previous
//
#include <hip/hip_runtime.h>
#include <math.h>

#define BATCH 4096
#define LDIM 1024
#define HDIM 2048
#define ODIM 512
#define GDIM 3072   // 3*LDIM
#define JDIM 1536   // IDIM+ODIM == LDIM+ODIM
#define INNER 4
#define OUTER 8

using f16 = _Float16;
using f16x4 = __attribute__((ext_vector_type(4))) _Float16;
using f16x8 = __attribute__((ext_vector_type(8))) _Float16;
using f32x4 = __attribute__((ext_vector_type(4))) float;

typedef __attribute__((address_space(3))) void lds_void;
typedef __attribute__((address_space(1))) void glob_void;

__device__ __forceinline__ void gload16(const void* g, void* l) {
  __builtin_amdgcn_global_load_lds((const glob_void*)g, (lds_void*)l, 16, 0, 0);
}

#define MFMA16(a, b, c) __builtin_amdgcn_mfma_f32_16x16x32_f16(a, b, c, 0, 0, 0)
// counted vmcnt wait: keeps prefetch loads in flight across raw s_barrier
#define WAIT_VM(N) asm volatile("s_waitcnt vmcnt(" #N ")" ::: "memory")
#define SBAR asm volatile("s_barrier" ::: "memory")

__device__ __forceinline__ float fast_sigmoid(float x) {
  return __builtin_amdgcn_rcpf(1.0f + __expf(-x));
}
__device__ __forceinline__ float fast_tanh(float x) {
  return 1.0f - 2.0f * __builtin_amdgcn_rcpf(1.0f + __expf(2.0f * x));
}

// fp32 -> fp16 (RTN), n4 = elems/4
__global__ __launch_bounds__(256) void convert_w(const float* __restrict__ src,
                                                 f16* __restrict__ dst, int n4) {
  int i = blockIdx.x * 256 + threadIdx.x;
  if (i >= n4) return;
  float4 v = ((const float4*)src)[i];
  f16x4 d = {(f16)v.x, (f16)v.y, (f16)v.z, (f16)v.w};
  *(f16x4*)&dst[(size_t)i * 4] = d;
}

// W2 = W_ih[:, 1024:1536] fp32 -> f16 contiguous [3072][512]
__global__ __launch_bounds__(256) void convert_w2(const float* __restrict__ src,
                                                  f16* __restrict__ dst) {
  int idx = blockIdx.x * 256 + threadIdx.x;  // over 3072*128 float4s
  if (idx >= GDIM * 128) return;
  int row = idx >> 7, c4 = idx & 127;
  float4 v = *(const float4*)&src[(size_t)row * JDIM + 1024 + c4 * 4];
  f16x4 d = {(f16)v.x, (f16)v.y, (f16)v.z, (f16)v.w};
  *(f16x4*)&dst[(size_t)row * 512 + c4 * 4] = d;
}

// ============================================================================
// 8-phase 256x256 fp16 GEMM (HK-style schedule, plain HIP), lda-generalized.
// C[4096, N] = epi(A @ W^T [+ bias]). A fp16 [M][lda-strided], W [N][ldw].
// 512 threads = 8 waves (2M x 4N); wave output 128x64 = acc[8][4] frags.
// BK=64 in 2 K-halves of 32; LDS = 2 dbuf x 2 khalf x 256x32 x {A,W} = 128KB.
// Per K-tile 4 phases; each stages ONE half-tile of t+1 into buf[p^1];
// vmcnt(4)+barrier at phases 0/2 (drains exactly the 2 half-tiles read),
// never vmcnt(0) mid-loop. Read-side XOR swizzle matched by pre-swizzled
// global source column (both-sides rule); LDS dest linear.
// EPI: 0 = PACKED fp16 C ([m/4][N][4]) + bias
//      1 = joint head relu: n<2048 -> h1 f16 (bias), else h2 f16 (bias2)
//      3 = delta-xg: PACKED fp16 C = acc + Xb (packed xg_base, NO bias)
// ============================================================================
template <int EPI>
__global__ __launch_bounds__(512, 1) void gemm_f16(
    const f16* __restrict__ A, const f16* __restrict__ W,
    const float* __restrict__ bias, const float* __restrict__ bias2,
    const f16* __restrict__ Xb,
    f16* __restrict__ Ch, f16* __restrict__ Cf, int N, int K, int lda, int ldw) {
  __shared__ f16 sA[2 * 2 * 256 * 32];  // 64 KB
  __shared__ f16 sW[2 * 2 * 256 * 32];  // 64 KB
  const int tid = threadIdx.x;
  const int w = tid >> 6, lane = tid & 63;
  const int wm = w >> 2, wn = w & 3;
  const int fr = lane & 15, quad = lane >> 4;
  const int nb = N >> 8;
  const int m0 = (blockIdx.x / nb) * 256, n0 = (blockIdx.x % nb) * 256;

  const int swz_src = (((tid & 3) ^ ((tid >> 3) & 3)) * 8);
  const f16* pAst = A + (size_t)(m0 + (tid >> 2)) * lda + swz_src;
  const f16* pWst = W + (size_t)(n0 + (tid >> 2)) * ldw + swz_src;
  const size_t h128a = (size_t)128 * lda;
  const size_t h128w = (size_t)128 * ldw;
  const int ldst = tid * 8;
  const int swr = ((quad ^ ((fr >> 1) & 3)) * 8);

  f32x4 acc[8][4] = {};
  const int NT = K >> 6;  // K-tiles of 64

#define STA(p, kh, kt)                                              \
  {                                                                 \
    int o = ((p) * 2 + (kh)) * 8192 + ldst;                         \
    gload16(pAst + (kt) * 64 + (kh) * 32, &sA[o]);                  \
    gload16(pAst + h128a + (kt) * 64 + (kh) * 32, &sA[o + 4096]);   \
  }
#define STW(p, kh, kt)                                              \
  {                                                                 \
    int o = ((p) * 2 + (kh)) * 8192 + ldst;                         \
    gload16(pWst + (kt) * 64 + (kh) * 32, &sW[o]);                  \
    gload16(pWst + h128w + (kt) * 64 + (kh) * 32, &sW[o + 4096]);   \
  }
#define LDB(p, kk)                                                  \
  _Pragma("unroll") for (int j = 0; j < 4; ++j) {                   \
    int rn = wn * 64 + j * 16 + fr;                                 \
    bf[j] = *(const f16x8*)&sW[((p) * 2 + (kk)) * 8192 + rn * 32 + swr]; \
  }
#define LDA(p, kk, mh)                                              \
  _Pragma("unroll") for (int i2 = 0; i2 < 4; ++i2) {                \
    int rm = wm * 128 + (mh) * 64 + i2 * 16 + fr;                   \
    af[i2] = *(const f16x8*)&sA[((p) * 2 + (kk)) * 8192 + rm * 32 + swr]; \
  }
#define DOMFMA(mh)                                                  \
  __builtin_amdgcn_s_setprio(1);                                    \
  _Pragma("unroll") for (int i2 = 0; i2 < 4; ++i2)                  \
  _Pragma("unroll") for (int j = 0; j < 4; ++j)                     \
      acc[(mh) * 4 + i2][j] = MFMA16(af[i2], bf[j], acc[(mh) * 4 + i2][j]); \
  __builtin_amdgcn_s_setprio(0);

  STA(0, 0, 0); STW(0, 0, 0); STA(0, 1, 0); STW(0, 1, 0);

  for (int t = 0; t < NT; ++t) {
    const int p = t & 1, pn = p ^ 1;
    const bool pf = (t + 1 < NT);
    f16x8 af[4], bf[4];
    // ---- phase 0: kk=0, mh=0; stage A-h0(t+1)
    if (t == NT - 1) { WAIT_VM(0); } else { WAIT_VM(4); }
    SBAR;
    if (pf) STA(pn, 0, t + 1);
    LDB(p, 0); LDA(p, 0, 0);
    DOMFMA(0);
    // ---- phase 1: kk=0, mh=1; stage W-h0(t+1)
    SBAR;
    if (pf) STW(pn, 0, t + 1);
    LDA(p, 0, 1);
    DOMFMA(1);
    // ---- phase 2: kk=1, mh=0; stage A-h1(t+1)
    if (t == NT - 1) { WAIT_VM(0); } else { WAIT_VM(4); }
    SBAR;
    if (pf) STA(pn, 1, t + 1);
    LDB(p, 1); LDA(p, 1, 0);
    DOMFMA(0);
    // ---- phase 3: kk=1, mh=1; stage W-h1(t+1)
    SBAR;
    if (pf) STW(pn, 1, t + 1);
    LDA(p, 1, 1);
    DOMFMA(1);
  }
#undef STA
#undef STW
#undef LDB
#undef LDA
#undef DOMFMA

  // C/D map: col = lane&15, row = quad*4 + reg
  bool is_h1 = true;
  const float* bp = bias;
  int nb0 = n0;
  if (EPI == 1) {
    is_h1 = (n0 < 2048);
    bp = is_h1 ? bias : bias2;
    nb0 = is_h1 ? n0 : n0 - 2048;
  }
#pragma unroll
  for (int j = 0; j < 4; ++j) {
    int n = nb0 + wn * 64 + j * 16 + fr;
    float bv = (EPI == 3) ? 0.0f : bp[n];
#pragma unroll
    for (int i = 0; i < 8; ++i) {
      int mb = m0 + wm * 128 + i * 16 + quad * 4;
      if (EPI == 0) {
        f16x4 o = {(f16)(acc[i][j][0] + bv), (f16)(acc[i][j][1] + bv),
                   (f16)(acc[i][j][2] + bv), (f16)(acc[i][j][3] + bv)};
        *(f16x4*)&Ch[((size_t)(mb >> 2) * N + n) * 4] = o;
      } else if (EPI == 3) {
        size_t off = ((size_t)(mb >> 2) * N + n) * 4;
        f16x4 b4 = *(const f16x4*)&Xb[off];
        f16x4 o = {(f16)(acc[i][j][0] + (float)b4[0]),
                   (f16)(acc[i][j][1] + (float)b4[1]),
                   (f16)(acc[i][j][2] + (float)b4[2]),
                   (f16)(acc[i][j][3] + (float)b4[3])};
        *(f16x4*)&Ch[off] = o;
      } else {
#pragma unroll
        for (int r = 0; r < 4; ++r) {
          int m = mb + r;
          float v = fmaxf(acc[i][j][r] + bv, 0.0f);
          if (is_h1)
            Ch[(size_t)m * HDIM + n] = (f16)v;
          else
            Cf[(size_t)m * LDIM + n] = (f16)v;
        }
      }
    }
  }
}

// ============================================================================
// Logits GEMM (N=512, K=2048): 128x128 tile, triple-buffer counted vmcnt.
// fp32 out + tanh -> fp16 into J0 ans cols (cols 1024:1536, row stride JDIM).
// ============================================================================
__global__ __launch_bounds__(256, 2) void gemm_logits(
    const f16* __restrict__ A, const f16* __restrict__ W,
    const float* __restrict__ bias, float* __restrict__ Cout,
    f16* __restrict__ aJH, int N, int K) {
  __shared__ f16 sA[3][128 * 32];
  __shared__ f16 sW[3][128 * 32];
  const int tid = threadIdx.x;
  const int w = tid >> 6, lane = tid & 63;
  const int wm = w >> 1, wn = w & 1;
  const int fr = lane & 15, quad = lane >> 4;
  const int m0 = blockIdx.y * 128, n0 = blockIdx.x * 128;
  const int srow = w * 32 + (lane >> 2);
  const int scol = (((lane & 3) ^ ((lane >> 3) & 3)) * 8);
  const f16* pA = A + (size_t)(m0 + srow) * K + scol;
  const f16* pW = W + (size_t)(n0 + srow) * K + scol;
  const size_t rstep = (size_t)16 * K;
  const int lo = w * 1024;

  f32x4 acc[4][4] = {};
  const int NT = K >> 5;

  auto stage = [&](int b, int k) {
    gload16(pA + k, &sA[b][lo]);
    gload16(pA + rstep + k, &sA[b][lo + 512]);
    gload16(pW + k, &sW[b][lo]);
    gload16(pW + rstep + k, &sW[b][lo + 512]);
  };
  stage(0, 0);
  stage(1, 32);
  int bb = 0;
  for (int t = 0; t < NT; ++t) {
    if (t == NT - 1) { WAIT_VM(0); } else { WAIT_VM(4); }
    __builtin_amdgcn_s_barrier();
    if (t + 2 < NT) {
      int bn = bb + 2; if (bn >= 3) bn -= 3;
      stage(bn, (t + 2) * 32);
    }
    f16x8 af[4], bf[4];
#pragma unroll
    for (int i = 0; i < 4; ++i) {
      int rr = wm * 64 + i * 16 + fr;
      af[i] = *(const f16x8*)&sA[bb][rr * 32 + ((quad ^ ((rr >> 1) & 3)) << 3)];
    }
#pragma unroll
    for (int j = 0; j < 4; ++j) {
      int rr = wn * 64 + j * 16 + fr;
      bf[j] = *(const f16x8*)&sW[bb][rr * 32 + ((quad ^ ((rr >> 1) & 3)) << 3)];
    }
    __builtin_amdgcn_s_setprio(1);
#pragma unroll
    for (int i = 0; i < 4; ++i)
#pragma unroll
      for (int j = 0; j < 4; ++j) acc[i][j] = MFMA16(af[i], bf[j], acc[i][j]);
    __builtin_amdgcn_s_setprio(0);
    if (++bb == 3) bb = 0;
  }

#pragma unroll
  for (int j = 0; j < 4; ++j) {
    int n = n0 + wn * 64 + j * 16 + fr;
    float bv = bias[n];
#pragma unroll
    for (int i = 0; i < 4; ++i) {
      int mb = m0 + wm * 64 + i * 16 + quad * 4;
#pragma unroll
      for (int r = 0; r < 4; ++r) {
        int m = mb + r;
        float v = acc[i][j][r] + bv;
        Cout[(size_t)m * N + n] = v;
        aJH[(size_t)m * JDIM + 1024 + n] = (f16)fast_tanh(v);
      }
    }
  }
}

// ============================================================================
// Fused GRU cycle on joint buffers: state lives in cols [0,1024) of J
// ([B,1536], row stride JDIM). h_gates = state @ W_hh^T + b_hh + gate update.
// Block: 128(M) x 64(N per gate) x 3 gates. 4 waves, wave = 32(M)x64(N).
// Triple-buffer + counted vmcnt(5) + LDS swizzle + XCD-aware 1D grid decode
// (each XCD owns 2 n-blocks -> W_hh slice L2-resident across 32 dispatches).
// ============================================================================
__global__ __launch_bounds__(256, 2) void gru_fused(
    const f16* __restrict__ inJ, const f16* __restrict__ Whh,
    const float* __restrict__ bhh, const f16* __restrict__ xgP,
    f16* __restrict__ outJ) {
  __shared__ f16 sA[3][128 * 32];
  __shared__ f16 sW0[3][64 * 32];
  __shared__ f16 sW1[3][64 * 32];
  __shared__ f16 sW2[3][64 * 32];
  const int tid = threadIdx.x;
  const int w = tid >> 6, lane = tid & 63;
  const int fr = lane & 15, quad = lane >> 4;
  // XCD decode: 8 XCDs x (2 n-blocks x 32 m-blocks)
  const int flat = blockIdx.x;
  const int xcd = flat & 7, local = flat >> 3;
  const int n0 = (xcd * 2 + (local & 1)) * 64;
  const int m0 = (local >> 1) * 128;
  const int srow = w * 32 + (lane >> 2);
  const int scol = (((lane & 3) ^ ((lane >> 3) & 3)) * 8);  // swizzled source
  const f16* pA = inJ + (size_t)(m0 + srow) * JDIM + scol;
  const size_t rstepA = (size_t)16 * JDIM;
  const int wrow = w * 16 + (lane >> 2);
  const f16* pW0 = Whh + (size_t)(n0 + wrow) * LDIM + scol;
  const f16* pW1 = pW0 + (size_t)LDIM * LDIM;
  const f16* pW2 = pW1 + (size_t)LDIM * LDIM;
  const int loA = w * 1024, loW = w * 512;

  f32x4 ar[2][4] = {}, az[2][4] = {}, an_[2][4] = {};
  const int NT = LDIM >> 5;  // 32

  auto stage = [&](int b, int k) {
    gload16(pA + k, &sA[b][loA]);
    gload16(pA + rstepA + k, &sA[b][loA + 512]);
    gload16(pW0 + k, &sW0[b][loW]);
    gload16(pW1 + k, &sW1[b][loW]);
    gload16(pW2 + k, &sW2[b][loW]);
  };
  stage(0, 0);
  stage(1, 32);
  int bb = 0;
  for (int t = 0; t < NT; ++t) {
    if (t == NT - 1) { WAIT_VM(0); } else { WAIT_VM(5); }
    __builtin_amdgcn_s_barrier();
    if (t + 2 < NT) {
      int bn = bb + 2; if (bn >= 3) bn -= 3;
      stage(bn, (t + 2) * 32);
    }
    f16x8 a_[2], w0[4], w1[4], w2[4];
#pragma unroll
    for (int i = 0; i < 2; ++i) {
      int rr = w * 32 + i * 16 + fr;
      a_[i] = *(const f16x8*)&sA[bb][rr * 32 + ((quad ^ ((rr >> 1) & 3)) << 3)];
    }
#pragma unroll
    for (int j = 0; j < 4; ++j) {
      int rw = j * 16 + fr;
      int wo = rw * 32 + ((quad ^ ((rw >> 1) & 3)) << 3);
      w0[j] = *(const f16x8*)&sW0[bb][wo];
      w1[j] = *(const f16x8*)&sW1[bb][wo];
      w2[j] = *(const f16x8*)&sW2[bb][wo];
    }
    __builtin_amdgcn_s_setprio(1);
#pragma unroll
    for (int i = 0; i < 2; ++i)
#pragma unroll
      for (int j = 0; j < 4; ++j) {
        ar[i][j] = MFMA16(a_[i], w0[j], ar[i][j]);
        az[i][j] = MFMA16(a_[i], w1[j], az[i][j]);
        an_[i][j] = MFMA16(a_[i], w2[j], an_[i][j]);
      }
    __builtin_amdgcn_s_setprio(0);
    if (++bb == 3) bb = 0;
  }

  // epilogue: full GRU gate update; xg loads are f16x4 (packed layout)
#pragma unroll
  for (int j = 0; j < 4; ++j) {
    int col = n0 + j * 16 + fr;
    float br = bhh[col], bz = bhh[col + LDIM], bn = bhh[col + 2 * LDIM];
#pragma unroll
    for (int i = 0; i < 2; ++i) {
      int mb = m0 + w * 32 + i * 16 + quad * 4;
      size_t xb = ((size_t)(mb >> 2) * GDIM + col) * 4;
      f16x4 x4r = *(const f16x4*)&xgP[xb];
      f16x4 x4z = *(const f16x4*)&xgP[xb + (size_t)LDIM * 4];
      f16x4 x4n = *(const f16x4*)&xgP[xb + (size_t)2 * LDIM * 4];
#pragma unroll
      for (int r = 0; r < 4; ++r) {
        int m = mb + r;
        size_t si = (size_t)m * JDIM + col;
        float sold = (float)inJ[si];
        float rg = fast_sigmoid((float)x4r[r] + ar[i][j][r] + br);
        float zg = fast_sigmoid((float)x4z[r] + az[i][j][r] + bz);
        float ng = fast_tanh((float)x4n[r] + rg * (an_[i][j][r] + bn));
        float o = (1.0f - zg) * ng + zg * sold;
        outJ[si] = (f16)o;
      }
    }
  }
}

// halt = h2[B,1024](f16) @ hw2[2,1024]^T + hb2; one wave per row.
__global__ __launch_bounds__(256) void halt_kernel(
    const f16* __restrict__ h2, const float* __restrict__ hw2,
    const float* __restrict__ hb2, float* __restrict__ out) {
  int wave = (blockIdx.x * 256 + threadIdx.x) >> 6;
  int lane = threadIdx.x & 63;
  if (wave >= BATCH) return;
  const f16* row = h2 + (size_t)wave * LDIM;
  float s0 = 0.0f, s1 = 0.0f;
#pragma unroll
  for (int k = lane; k < LDIM; k += 64) {
    float v = (float)row[k];
    s0 = fmaf(v, hw2[k], s0);
    s1 = fmaf(v, hw2[LDIM + k], s1);
  }
#pragma unroll
  for (int off = 32; off > 0; off >>= 1) {
    s0 += __shfl_xor(s0, off);
    s1 += __shfl_xor(s1, off);
  }
  if (lane == 0) {
    out[(size_t)wave * 2 + 0] = s0 + hb2[0];
    out[(size_t)wave * 2 + 1] = s1 + hb2[1];
  }
}

extern "C" void kernel_launch(void* const* d_in, const int* in_sizes, int n_in,
                              void* d_out, int out_size, void* d_ws, size_t ws_size,
                              hipStream_t stream) {
  const float* inputs = (const float*)d_in[0];
  const float* W_ih = (const float*)d_in[1];
  const float* W_hh = (const float*)d_in[2];
  const float* b_ih = (const float*)d_in[3];
  const float* b_hh = (const float*)d_in[4];
  const float* aw1 = (const float*)d_in[5];
  const float* ab1 = (const float*)d_in[6];
  const float* aw2 = (const float*)d_in[7];
  const float* ab2 = (const float*)d_in[8];
  const float* hw1 = (const float*)d_in[9];
  const float* hb1 = (const float*)d_in[10];
  const float* hw2 = (const float*)d_in[11];
  const float* hb2 = (const float*)d_in[12];

  float* out = (float*)d_out;
  float* logits_out = out;                               // [8, B, 512]
  float* halt_out = out + (size_t)OUTER * BATCH * ODIM;  // [8, B, 2]

  char* p = (char*)d_ws;
  auto take = [&](size_t bytes) { char* q = p; p += (bytes + 255) & ~255ull; return q; };
  // xg union region (25.2 MB): holds {inpF16 [B,1024] + WihF [3072,1536]}
  // during setup/base-GEMM; becomes xg (packed delta result) / h1 overlay
  // during the step loop. xgBase is never overlaid.
  f16* xg = (f16*)take((size_t)BATCH * GDIM * 2);
  f16* inpF16 = xg;                                   // [B,1024] f16 (setup)
  f16* WihF = xg + (size_t)BATCH * LDIM;              // [3072,1536] f16 (setup)
  f16* xgBase = (f16*)take((size_t)BATCH * GDIM * 2); // 25.2 MB, PACKED
  f16* J0 = (f16*)take((size_t)BATCH * JDIM * 2);     // [B,1536] joint
  f16* J1 = (f16*)take((size_t)BATCH * JDIM * 2);
  f16* h2F = (f16*)take((size_t)BATCH * LDIM * 2);    // h2 f16 [B,1024]
  f16* WhhF = (f16*)take((size_t)GDIM * LDIM * 2);
  f16* WjF = (f16*)take((size_t)(HDIM + LDIM) * JDIM * 2);  // [aw1; hw1]
  f16* aw2F = (f16*)take((size_t)ODIM * HDIM * 2);
  f16* W2F = (f16*)take((size_t)GDIM * 512 * 2);      // W_ih[:,1024:1536]
  f16* h1 = xg;                                        // overlay (see above)
  if ((size_t)(p - (char*)d_ws) > ws_size) return;     // workspace guard

  (void)hipMemsetAsync(J0, 0, (size_t)BATCH * JDIM * 2, stream);

  auto conv = [&](const float* s, f16* d, size_t n) {
    int n4 = (int)(n / 4);
    convert_w<<<(n4 + 255) / 256, 256, 0, stream>>>(s, d, n4);
  };
  conv(inputs, inpF16, (size_t)BATCH * LDIM);
  conv(W_ih, WihF, (size_t)GDIM * JDIM);
  convert_w2<<<(GDIM * 128 + 255) / 256, 256, 0, stream>>>(W_ih, W2F);
  conv(W_hh, WhhF, (size_t)GDIM * LDIM);
  conv(aw1, WjF, (size_t)HDIM * JDIM);
  conv(hw1, WjF + (size_t)HDIM * JDIM, (size_t)LDIM * JDIM);
  conv(aw2, aw2F, (size_t)ODIM * HDIM);

  // xg_base = inputs @ W1^T + b_ih (K=1024: ans cols are zero at s=0,
  // and W1 = W_ih[:, :1024] with row stride JDIM). Computed ONCE. PACKED.
  gemm_f16<0><<<(BATCH / 256) * (GDIM / 256), 512, 0, stream>>>(
      inpF16, WihF, b_ih, nullptr, nullptr, xgBase, nullptr,
      GDIM, LDIM, LDIM, JDIM);

  for (int s = 0; s < OUTER; ++s) {
    // xg = xg_base + ans @ W2^T (K=512 delta; skipped at s=0: ans=0).
    // A = J0 ans cols (row stride JDIM).
    const f16* xgUse = xgBase;
    if (s > 0) {
      gemm_f16<3><<<(BATCH / 256) * (GDIM / 256), 512, 0, stream>>>(
          J0 + 1024, W2F, nullptr, nullptr, xgBase, xg, nullptr,
          GDIM, 512, JDIM, 512);
      xgUse = xg;
    }
    // 4 fused GRU cycles on joint ping-pong; c3 lands state back in J0
    gru_fused<<<512, 256, 0, stream>>>(J0, WhhF, b_hh, xgUse, J1);
    gru_fused<<<512, 256, 0, stream>>>(J1, WhhF, b_hh, xgUse, J0);
    gru_fused<<<512, 256, 0, stream>>>(J0, WhhF, b_hh, xgUse, J1);
    gru_fused<<<512, 256, 0, stream>>>(J1, WhhF, b_hh, xgUse, J0);
    // h1 = relu(joint @ aw1^T + ab1) f16 (overlay xg);
    // h2 = relu(joint @ hw1^T + hb1) f16 — one combined N=3072 GEMM
    gemm_f16<1><<<(BATCH / 256) * ((HDIM + LDIM) / 256), 512, 0, stream>>>(
        J0, WjF, ab1, hb1, nullptr, h1, h2F, HDIM + LDIM, JDIM, JDIM, JDIM);
    // logits = h1 @ aw2^T + ab2 -> out; ans = tanh -> J0 ans cols
    gemm_logits<<<dim3(ODIM / 128, BATCH / 128), 256, 0, stream>>>(
        h1, aw2F, ab2, logits_out + (size_t)s * BATCH * ODIM, J0, ODIM, HDIM);
    // halt = h2 @ hw2^T + hb2 -> out
    halt_kernel<<<BATCH / 4, 256, 0, stream>>>(
        h2F, hw2, hb2, halt_out + (size_t)s * BATCH * 2);
  }
}

// Round 7
// 2371.482 us; speedup vs baseline: 1.1950x; 1.0675x over previous
//
#include <hip/hip_runtime.h>
#include <math.h>

#define BATCH 4096
#define LDIM 1024
#define HDIM 2048
#define ODIM 512
#define GDIM 3072   // 3*LDIM
#define JDIM 1536   // IDIM+ODIM == LDIM+ODIM
#define INNER 4
#define OUTER 8

using f16 = _Float16;
using f16x4 = __attribute__((ext_vector_type(4))) _Float16;
using f16x8 = __attribute__((ext_vector_type(8))) _Float16;
using f32x4 = __attribute__((ext_vector_type(4))) float;

typedef __attribute__((address_space(3))) void lds_void;
typedef __attribute__((address_space(1))) void glob_void;

__device__ __forceinline__ void gload16(const void* g, void* l) {
  __builtin_amdgcn_global_load_lds((const glob_void*)g, (lds_void*)l, 16, 0, 0);
}

#define MFMA16(a, b, c) __builtin_amdgcn_mfma_f32_16x16x32_f16(a, b, c, 0, 0, 0)
// counted vmcnt wait: keeps prefetch loads in flight across raw s_barrier
#define WAIT_VM(N) asm volatile("s_waitcnt vmcnt(" #N ")" ::: "memory")
#define SBAR asm volatile("s_barrier" ::: "memory")

__device__ __forceinline__ float fast_sigmoid(float x) {
  return __builtin_amdgcn_rcpf(1.0f + __expf(-x));
}
__device__ __forceinline__ float fast_tanh(float x) {
  return 1.0f - 2.0f * __builtin_amdgcn_rcpf(1.0f + __expf(2.0f * x));
}

// fp32 -> fp16 (RTN), n4 = elems/4
__global__ __launch_bounds__(256) void convert_w(const float* __restrict__ src,
                                                 f16* __restrict__ dst, int n4) {
  int i = blockIdx.x * 256 + threadIdx.x;
  if (i >= n4) return;
  float4 v = ((const float4*)src)[i];
  f16x4 d = {(f16)v.x, (f16)v.y, (f16)v.z, (f16)v.w};
  *(f16x4*)&dst[(size_t)i * 4] = d;
}

// W2 = W_ih[:, 1024:1536] fp32 -> f16 contiguous [3072][512]
__global__ __launch_bounds__(256) void convert_w2(const float* __restrict__ src,
                                                  f16* __restrict__ dst) {
  int idx = blockIdx.x * 256 + threadIdx.x;  // over 3072*128 float4s
  if (idx >= GDIM * 128) return;
  int row = idx >> 7, c4 = idx & 127;
  float4 v = *(const float4*)&src[(size_t)row * JDIM + 1024 + c4 * 4];
  f16x4 d = {(f16)v.x, (f16)v.y, (f16)v.z, (f16)v.w};
  *(f16x4*)&dst[(size_t)row * 512 + c4 * 4] = d;
}

// ============================================================================
// 8-phase 128(M)x384(N) fp16 GEMM, N=3072 -> grid = 32x8 = 256 blocks =
// exactly 1/CU (full machine coverage; the old 256x256 tile left 64 CUs idle).
// C[4096, 3072] = epi(A @ W^T [+ bias]). A fp16 [M][lda], W fp16 [N][ldw].
// 512 threads = 8 waves (2M x 4N); wave output 64x96 = acc[4][6] frags.
// BK=64 in 2 K-halves of 32; LDS = A 32KB + W 96KB = 128 KB (2 dbuf).
// Per K-tile 4 phases (kk x n-half); stage stream per tile: A-h0(1 load/thr),
// W-h0(3), A-h1(1), W-h1(3) = 8 -> WAIT_VM(4) at phases 0/2 drains exactly
// the half-tiles being read; never vmcnt(0) mid-loop. Read-side XOR swizzle
// matched by pre-swizzled global source column; LDS dest linear.
// With 8 n-blocks, bid%8 = n-block = XCD -> each XCD's W panel (1.15MB)
// is naturally L2-resident.
// EPI: 0 = PACKED fp16 C ([m/4][N][4]) + bias
//      1 = joint head relu: n<2048 -> h1 f16 (bias), else h2 f16 (bias2)
//      3 = delta-xg: PACKED fp16 C = acc + Xb (packed xg_base, NO bias)
// ============================================================================
template <int EPI>
__global__ __launch_bounds__(512, 1) void gemm_f16(
    const f16* __restrict__ A, const f16* __restrict__ W,
    const float* __restrict__ bias, const float* __restrict__ bias2,
    const f16* __restrict__ Xb,
    f16* __restrict__ Ch, f16* __restrict__ Cf, int N, int K, int lda, int ldw) {
  __shared__ f16 sA[2 * 2 * 128 * 32];  // 32 KB
  __shared__ f16 sW[2 * 2 * 384 * 32];  // 96 KB
  const int tid = threadIdx.x;
  const int w = tid >> 6, lane = tid & 63;
  const int wm = w >> 2, wn = w & 3;
  const int fr = lane & 15, quad = lane >> 4;
  const int nb = N / 384;  // 8
  const int m0 = (blockIdx.x / nb) * 128, n0 = (blockIdx.x % nb) * 384;

  // staging: thread t covers row tid>>2, 16B chunk tid&3; source column
  // pre-swizzled to match the read-side XOR (both-sides rule).
  const int swz_src = (((tid & 3) ^ ((tid >> 3) & 3)) * 8);
  const f16* pAst = A + (size_t)(m0 + (tid >> 2)) * lda + swz_src;
  const f16* pWst = W + (size_t)(n0 + (tid >> 2)) * ldw + swz_src;
  const size_t h128w = (size_t)128 * ldw;
  const int swr = ((quad ^ ((fr >> 1) & 3)) * 8);

  f32x4 acc[4][6] = {};
  const int NT = K >> 6;  // K-tiles of 64

#define STA(p, kh, kt)                                                \
  {                                                                   \
    int o = ((p) * 2 + (kh)) * 4096 + tid * 8;                        \
    gload16(pAst + (kt) * 64 + (kh) * 32, &sA[o]);                    \
  }
#define STW(p, kh, kt)                                                \
  {                                                                   \
    int o = ((p) * 2 + (kh)) * 12288 + tid * 8;                       \
    gload16(pWst + (kt) * 64 + (kh) * 32, &sW[o]);                    \
    gload16(pWst + h128w + (kt) * 64 + (kh) * 32, &sW[o + 4096]);     \
    gload16(pWst + 2 * h128w + (kt) * 64 + (kh) * 32, &sW[o + 8192]); \
  }
#define LDA(p, kk)                                                    \
  _Pragma("unroll") for (int i2 = 0; i2 < 4; ++i2) {                  \
    int rm = wm * 64 + i2 * 16 + fr;                                  \
    af[i2] = *(const f16x8*)&sA[((p) * 2 + (kk)) * 4096 + rm * 32 + swr]; \
  }
#define LDB(p, kk, nh)                                                \
  _Pragma("unroll") for (int j2 = 0; j2 < 3; ++j2) {                  \
    int rn = wn * 96 + ((nh) * 3 + j2) * 16 + fr;                     \
    bf[j2] = *(const f16x8*)&sW[((p) * 2 + (kk)) * 12288 + rn * 32 + swr]; \
  }
#define DOMFMA(nh)                                                    \
  __builtin_amdgcn_s_setprio(1);                                      \
  _Pragma("unroll") for (int i2 = 0; i2 < 4; ++i2)                    \
  _Pragma("unroll") for (int j2 = 0; j2 < 3; ++j2)                    \
      acc[i2][(nh) * 3 + j2] = MFMA16(af[i2], bf[j2], acc[i2][(nh) * 3 + j2]); \
  __builtin_amdgcn_s_setprio(0);

  // prologue: stage all 4 half-tiles of tile 0 into buf 0 (8 loads/thread)
  STA(0, 0, 0); STW(0, 0, 0); STA(0, 1, 0); STW(0, 1, 0);

  for (int t = 0; t < NT; ++t) {
    const int p = t & 1, pn = p ^ 1;
    const bool pf = (t + 1 < NT);
    f16x8 af[4], bf[3];
    // ---- phase 0: kk=0, nh=0; stage A-h0(t+1)
    if (t == NT - 1) { WAIT_VM(0); } else { WAIT_VM(4); }
    SBAR;
    if (pf) STA(pn, 0, t + 1);
    LDA(p, 0); LDB(p, 0, 0);
    DOMFMA(0);
    // ---- phase 1: kk=0, nh=1; stage W-h0(t+1); af reused
    SBAR;
    if (pf) STW(pn, 0, t + 1);
    LDB(p, 0, 1);
    DOMFMA(1);
    // ---- phase 2: kk=1, nh=0; stage A-h1(t+1)
    if (t == NT - 1) { WAIT_VM(0); } else { WAIT_VM(4); }
    SBAR;
    if (pf) STA(pn, 1, t + 1);
    LDA(p, 1); LDB(p, 1, 0);
    DOMFMA(0);
    // ---- phase 3: kk=1, nh=1; stage W-h1(t+1); af reused
    SBAR;
    if (pf) STW(pn, 1, t + 1);
    LDB(p, 1, 1);
    DOMFMA(1);
  }
#undef STA
#undef STW
#undef LDA
#undef LDB
#undef DOMFMA

  // C/D map: col = lane&15, row = quad*4 + reg
#pragma unroll
  for (int j = 0; j < 6; ++j) {
    int n = n0 + wn * 96 + j * 16 + fr;
    float bv;
    if (EPI == 3) bv = 0.0f;
    else if (EPI == 1) bv = (n < 2048) ? bias[n] : bias2[n - 2048];
    else bv = bias[n];
#pragma unroll
    for (int i = 0; i < 4; ++i) {
      int mb = m0 + wm * 64 + i * 16 + quad * 4;
      if (EPI == 0) {
        f16x4 o = {(f16)(acc[i][j][0] + bv), (f16)(acc[i][j][1] + bv),
                   (f16)(acc[i][j][2] + bv), (f16)(acc[i][j][3] + bv)};
        *(f16x4*)&Ch[((size_t)(mb >> 2) * N + n) * 4] = o;
      } else if (EPI == 3) {
        size_t off = ((size_t)(mb >> 2) * N + n) * 4;
        f16x4 b4 = *(const f16x4*)&Xb[off];
        f16x4 o = {(f16)(acc[i][j][0] + (float)b4[0]),
                   (f16)(acc[i][j][1] + (float)b4[1]),
                   (f16)(acc[i][j][2] + (float)b4[2]),
                   (f16)(acc[i][j][3] + (float)b4[3])};
        *(f16x4*)&Ch[off] = o;
      } else {
#pragma unroll
        for (int r = 0; r < 4; ++r) {
          int m = mb + r;
          float v = fmaxf(acc[i][j][r] + bv, 0.0f);
          if (n < 2048)
            Ch[(size_t)m * HDIM + n] = (f16)v;
          else
            Cf[(size_t)m * LDIM + (n - 2048)] = (f16)v;
        }
      }
    }
  }
}

// ============================================================================
// Logits GEMM (N=512, K=2048): 128(M)x64(N) tile -> grid 8x32 = 256 blocks
// at 2/CU (old 128x128 grid of 128 blocks used only 64 CUs).
// 256 threads, 4 waves; wave = 32Mx64N, acc[2][4]. Triple-buffer, vmcnt(3).
// fp32 out + tanh -> fp16 into J0 ans cols (cols 1024:1536, stride JDIM).
// ============================================================================
__global__ __launch_bounds__(256, 2) void gemm_logits(
    const f16* __restrict__ A, const f16* __restrict__ W,
    const float* __restrict__ bias, float* __restrict__ Cout,
    f16* __restrict__ aJH, int N, int K) {
  __shared__ f16 sA[3][128 * 32];  // 24 KB
  __shared__ f16 sW[3][64 * 32];   // 12 KB
  const int tid = threadIdx.x;
  const int w = tid >> 6, lane = tid & 63;
  const int fr = lane & 15, quad = lane >> 4;
  const int m0 = blockIdx.y * 128, n0 = blockIdx.x * 64;
  const int swz_src = (((tid & 3) ^ ((tid >> 3) & 3)) * 8);
  const f16* pA = A + (size_t)(m0 + (tid >> 2)) * K + swz_src;
  const f16* pW = W + (size_t)(n0 + (tid >> 2)) * K + swz_src;
  const size_t rstep = (size_t)64 * K;
  const int swr = ((quad ^ ((fr >> 1) & 3)) * 8);

  f32x4 acc[2][4] = {};
  const int NT = K >> 5;

  auto stage = [&](int b, int k) {
    gload16(pA + k, &sA[b][tid * 8]);          // A rows 0-63 chunk
    gload16(pA + rstep + k, &sA[b][tid * 8 + 2048]);  // A rows 64-127
    gload16(pW + k, &sW[b][tid * 8]);          // W rows 0-63
  };
  stage(0, 0);
  stage(1, 32);
  int bb = 0;
  for (int t = 0; t < NT; ++t) {
    if (t == NT - 1) { WAIT_VM(0); } else { WAIT_VM(3); }
    __builtin_amdgcn_s_barrier();
    if (t + 2 < NT) {
      int bn = bb + 2; if (bn >= 3) bn -= 3;
      stage(bn, (t + 2) * 32);
    }
    f16x8 af[2], bf[4];
#pragma unroll
    for (int i = 0; i < 2; ++i) {
      int rm = w * 32 + i * 16 + fr;
      af[i] = *(const f16x8*)&sA[bb][rm * 32 + swr];
    }
#pragma unroll
    for (int j = 0; j < 4; ++j) {
      int rn = j * 16 + fr;
      bf[j] = *(const f16x8*)&sW[bb][rn * 32 + swr];
    }
    __builtin_amdgcn_s_setprio(1);
#pragma unroll
    for (int i = 0; i < 2; ++i)
#pragma unroll
      for (int j = 0; j < 4; ++j) acc[i][j] = MFMA16(af[i], bf[j], acc[i][j]);
    __builtin_amdgcn_s_setprio(0);
    if (++bb == 3) bb = 0;
  }

#pragma unroll
  for (int j = 0; j < 4; ++j) {
    int n = n0 + j * 16 + fr;
    float bv = bias[n];
#pragma unroll
    for (int i = 0; i < 2; ++i) {
      int mb = m0 + w * 32 + i * 16 + quad * 4;
#pragma unroll
      for (int r = 0; r < 4; ++r) {
        int m = mb + r;
        float v = acc[i][j][r] + bv;
        Cout[(size_t)m * N + n] = v;
        aJH[(size_t)m * JDIM + 1024 + n] = (f16)fast_tanh(v);
      }
    }
  }
}

// ============================================================================
// Fused GRU cycle on joint buffers: state lives in cols [0,1024) of J
// ([B,1536], row stride JDIM). h_gates = state @ W_hh^T + b_hh + gate update.
// Block: 128(M) x 64(N per gate) x 3 gates. 4 waves, wave = 32(M)x64(N).
// Triple-buffer + counted vmcnt(5) + LDS swizzle + XCD-aware 1D grid decode
// (each XCD owns 2 n-blocks -> W_hh slice L2-resident across 32 dispatches).
// ============================================================================
__global__ __launch_bounds__(256, 2) void gru_fused(
    const f16* __restrict__ inJ, const f16* __restrict__ Whh,
    const float* __restrict__ bhh, const f16* __restrict__ xgP,
    f16* __restrict__ outJ) {
  __shared__ f16 sA[3][128 * 32];
  __shared__ f16 sW0[3][64 * 32];
  __shared__ f16 sW1[3][64 * 32];
  __shared__ f16 sW2[3][64 * 32];
  const int tid = threadIdx.x;
  const int w = tid >> 6, lane = tid & 63;
  const int fr = lane & 15, quad = lane >> 4;
  // XCD decode: 8 XCDs x (2 n-blocks x 32 m-blocks)
  const int flat = blockIdx.x;
  const int xcd = flat & 7, local = flat >> 3;
  const int n0 = (xcd * 2 + (local & 1)) * 64;
  const int m0 = (local >> 1) * 128;
  const int srow = w * 32 + (lane >> 2);
  const int scol = (((lane & 3) ^ ((lane >> 3) & 3)) * 8);  // swizzled source
  const f16* pA = inJ + (size_t)(m0 + srow) * JDIM + scol;
  const size_t rstepA = (size_t)16 * JDIM;
  const int wrow = w * 16 + (lane >> 2);
  const f16* pW0 = Whh + (size_t)(n0 + wrow) * LDIM + scol;
  const f16* pW1 = pW0 + (size_t)LDIM * LDIM;
  const f16* pW2 = pW1 + (size_t)LDIM * LDIM;
  const int loA = w * 1024, loW = w * 512;

  f32x4 ar[2][4] = {}, az[2][4] = {}, an_[2][4] = {};
  const int NT = LDIM >> 5;  // 32

  auto stage = [&](int b, int k) {
    gload16(pA + k, &sA[b][loA]);
    gload16(pA + rstepA + k, &sA[b][loA + 512]);
    gload16(pW0 + k, &sW0[b][loW]);
    gload16(pW1 + k, &sW1[b][loW]);
    gload16(pW2 + k, &sW2[b][loW]);
  };
  stage(0, 0);
  stage(1, 32);
  int bb = 0;
  for (int t = 0; t < NT; ++t) {
    if (t == NT - 1) { WAIT_VM(0); } else { WAIT_VM(5); }
    __builtin_amdgcn_s_barrier();
    if (t + 2 < NT) {
      int bn = bb + 2; if (bn >= 3) bn -= 3;
      stage(bn, (t + 2) * 32);
    }
    f16x8 a_[2], w0[4], w1[4], w2[4];
#pragma unroll
    for (int i = 0; i < 2; ++i) {
      int rr = w * 32 + i * 16 + fr;
      a_[i] = *(const f16x8*)&sA[bb][rr * 32 + ((quad ^ ((rr >> 1) & 3)) << 3)];
    }
#pragma unroll
    for (int j = 0; j < 4; ++j) {
      int rw = j * 16 + fr;
      int wo = rw * 32 + ((quad ^ ((rw >> 1) & 3)) << 3);
      w0[j] = *(const f16x8*)&sW0[bb][wo];
      w1[j] = *(const f16x8*)&sW1[bb][wo];
      w2[j] = *(const f16x8*)&sW2[bb][wo];
    }
    __builtin_amdgcn_s_setprio(1);
#pragma unroll
    for (int i = 0; i < 2; ++i)
#pragma unroll
      for (int j = 0; j < 4; ++j) {
        ar[i][j] = MFMA16(a_[i], w0[j], ar[i][j]);
        az[i][j] = MFMA16(a_[i], w1[j], az[i][j]);
        an_[i][j] = MFMA16(a_[i], w2[j], an_[i][j]);
      }
    __builtin_amdgcn_s_setprio(0);
    if (++bb == 3) bb = 0;
  }

  // epilogue: full GRU gate update; xg loads are f16x4 (packed layout)
#pragma unroll
  for (int j = 0; j < 4; ++j) {
    int col = n0 + j * 16 + fr;
    float br = bhh[col], bz = bhh[col + LDIM], bn = bhh[col + 2 * LDIM];
#pragma unroll
    for (int i = 0; i < 2; ++i) {
      int mb = m0 + w * 32 + i * 16 + quad * 4;
      size_t xb = ((size_t)(mb >> 2) * GDIM + col) * 4;
      f16x4 x4r = *(const f16x4*)&xgP[xb];
      f16x4 x4z = *(const f16x4*)&xgP[xb + (size_t)LDIM * 4];
      f16x4 x4n = *(const f16x4*)&xgP[xb + (size_t)2 * LDIM * 4];
#pragma unroll
      for (int r = 0; r < 4; ++r) {
        int m = mb + r;
        size_t si = (size_t)m * JDIM + col;
        float sold = (float)inJ[si];
        float rg = fast_sigmoid((float)x4r[r] + ar[i][j][r] + br);
        float zg = fast_sigmoid((float)x4z[r] + az[i][j][r] + bz);
        float ng = fast_tanh((float)x4n[r] + rg * (an_[i][j][r] + bn));
        float o = (1.0f - zg) * ng + zg * sold;
        outJ[si] = (f16)o;
      }
    }
  }
}

// halt = h2[B,1024](f16) @ hw2[2,1024]^T + hb2; one wave per row.
__global__ __launch_bounds__(256) void halt_kernel(
    const f16* __restrict__ h2, const float* __restrict__ hw2,
    const float* __restrict__ hb2, float* __restrict__ out) {
  int wave = (blockIdx.x * 256 + threadIdx.x) >> 6;
  int lane = threadIdx.x & 63;
  if (wave >= BATCH) return;
  const f16* row = h2 + (size_t)wave * LDIM;
  float s0 = 0.0f, s1 = 0.0f;
#pragma unroll
  for (int k = lane; k < LDIM; k += 64) {
    float v = (float)row[k];
    s0 = fmaf(v, hw2[k], s0);
    s1 = fmaf(v, hw2[LDIM + k], s1);
  }
#pragma unroll
  for (int off = 32; off > 0; off >>= 1) {
    s0 += __shfl_xor(s0, off);
    s1 += __shfl_xor(s1, off);
  }
  if (lane == 0) {
    out[(size_t)wave * 2 + 0] = s0 + hb2[0];
    out[(size_t)wave * 2 + 1] = s1 + hb2[1];
  }
}

extern "C" void kernel_launch(void* const* d_in, const int* in_sizes, int n_in,
                              void* d_out, int out_size, void* d_ws, size_t ws_size,
                              hipStream_t stream) {
  const float* inputs = (const float*)d_in[0];
  const float* W_ih = (const float*)d_in[1];
  const float* W_hh = (const float*)d_in[2];
  const float* b_ih = (const float*)d_in[3];
  const float* b_hh = (const float*)d_in[4];
  const float* aw1 = (const float*)d_in[5];
  const float* ab1 = (const float*)d_in[6];
  const float* aw2 = (const float*)d_in[7];
  const float* ab2 = (const float*)d_in[8];
  const float* hw1 = (const float*)d_in[9];
  const float* hb1 = (const float*)d_in[10];
  const float* hw2 = (const float*)d_in[11];
  const float* hb2 = (const float*)d_in[12];

  float* out = (float*)d_out;
  float* logits_out = out;                               // [8, B, 512]
  float* halt_out = out + (size_t)OUTER * BATCH * ODIM;  // [8, B, 2]

  char* p = (char*)d_ws;
  auto take = [&](size_t bytes) { char* q = p; p += (bytes + 255) & ~255ull; return q; };
  // xg union region (25.2 MB): holds {inpF16 [B,1024] + WihF [3072,1536]}
  // during setup/base-GEMM; becomes xg (packed delta result) / h1 overlay
  // during the step loop. xgBase is never overlaid.
  f16* xg = (f16*)take((size_t)BATCH * GDIM * 2);
  f16* inpF16 = xg;                                   // [B,1024] f16 (setup)
  f16* WihF = xg + (size_t)BATCH * LDIM;              // [3072,1536] f16 (setup)
  f16* xgBase = (f16*)take((size_t)BATCH * GDIM * 2); // 25.2 MB, PACKED
  f16* J0 = (f16*)take((size_t)BATCH * JDIM * 2);     // [B,1536] joint
  f16* J1 = (f16*)take((size_t)BATCH * JDIM * 2);
  f16* h2F = (f16*)take((size_t)BATCH * LDIM * 2);    // h2 f16 [B,1024]
  f16* WhhF = (f16*)take((size_t)GDIM * LDIM * 2);
  f16* WjF = (f16*)take((size_t)(HDIM + LDIM) * JDIM * 2);  // [aw1; hw1]
  f16* aw2F = (f16*)take((size_t)ODIM * HDIM * 2);
  f16* W2F = (f16*)take((size_t)GDIM * 512 * 2);      // W_ih[:,1024:1536]
  f16* h1 = xg;                                        // overlay (see above)
  if ((size_t)(p - (char*)d_ws) > ws_size) return;     // workspace guard

  (void)hipMemsetAsync(J0, 0, (size_t)BATCH * JDIM * 2, stream);

  auto conv = [&](const float* s, f16* d, size_t n) {
    int n4 = (int)(n / 4);
    convert_w<<<(n4 + 255) / 256, 256, 0, stream>>>(s, d, n4);
  };
  conv(inputs, inpF16, (size_t)BATCH * LDIM);
  conv(W_ih, WihF, (size_t)GDIM * JDIM);
  convert_w2<<<(GDIM * 128 + 255) / 256, 256, 0, stream>>>(W_ih, W2F);
  conv(W_hh, WhhF, (size_t)GDIM * LDIM);
  conv(aw1, WjF, (size_t)HDIM * JDIM);
  conv(hw1, WjF + (size_t)HDIM * JDIM, (size_t)LDIM * JDIM);
  conv(aw2, aw2F, (size_t)ODIM * HDIM);

  // xg_base = inputs @ W1^T + b_ih (K=1024: ans cols are zero at s=0,
  // and W1 = W_ih[:, :1024] with row stride JDIM). Computed ONCE. PACKED.
  gemm_f16<0><<<(BATCH / 128) * (GDIM / 384), 512, 0, stream>>>(
      inpF16, WihF, b_ih, nullptr, nullptr, xgBase, nullptr,
      GDIM, LDIM, LDIM, JDIM);

  for (int s = 0; s < OUTER; ++s) {
    // xg = xg_base + ans @ W2^T (K=512 delta; skipped at s=0: ans=0).
    // A = J0 ans cols (row stride JDIM).
    const f16* xgUse = xgBase;
    if (s > 0) {
      gemm_f16<3><<<(BATCH / 128) * (GDIM / 384), 512, 0, stream>>>(
          J0 + 1024, W2F, nullptr, nullptr, xgBase, xg, nullptr,
          GDIM, 512, JDIM, 512);
      xgUse = xg;
    }
    // 4 fused GRU cycles on joint ping-pong; c3 lands state back in J0
    gru_fused<<<512, 256, 0, stream>>>(J0, WhhF, b_hh, xgUse, J1);
    gru_fused<<<512, 256, 0, stream>>>(J1, WhhF, b_hh, xgUse, J0);
    gru_fused<<<512, 256, 0, stream>>>(J0, WhhF, b_hh, xgUse, J1);
    gru_fused<<<512, 256, 0, stream>>>(J1, WhhF, b_hh, xgUse, J0);
    // h1 = relu(joint @ aw1^T + ab1) f16 (overlay xg);
    // h2 = relu(joint @ hw1^T + hb1) f16 — one combined N=3072 GEMM
    gemm_f16<1><<<(BATCH / 128) * ((HDIM + LDIM) / 384), 512, 0, stream>>>(
        J0, WjF, ab1, hb1, nullptr, h1, h2F, HDIM + LDIM, JDIM, JDIM, JDIM);
    // logits = h1 @ aw2^T + ab2 -> out; ans = tanh -> J0 ans cols
    gemm_logits<<<dim3(ODIM / 64, BATCH / 128), 256, 0, stream>>>(
        h1, aw2F, ab2, logits_out + (size_t)s * BATCH * ODIM, J0, ODIM, HDIM);
    // halt = h2 @ hw2^T + hb2 -> out
    halt_kernel<<<BATCH / 4, 256, 0, stream>>>(
        h2F, hw2, hb2, halt_out + (size_t)s * BATCH * 2);
  }
}